// Round 3
// baseline (64.316 us; speedup 1.0000x reference)
//
#include <hip/hip_runtime.h>

// SceneContraction: f(x) = x if ||x||<1 else (2 - 1/||x||) x/||x||
// cov' = J cov J^T for ||x||>=1 (J = s I + c x x^T, s=(2n-1)/n^2, c=2(1-n)/n^4),
// cov otherwise.
// R2: latency-bound fix — 4 points/thread, all-float4 register path, no LDS.
//   Per thread: 12 independent global_load_dwordx4 (192 B in flight),
//   fully-unrolled compute (static indices -> registers), 12 dwordx4 stores.

#define BLOCK 256

__device__ __forceinline__ void contract_one(
    float x, float y, float z,
    float c00, float c01, float c02,
    float c10, float c11, float c12,
    float c20, float c21, float c22,
    float& ox, float& oy, float& oz,
    float& t00, float& t01, float& t02,
    float& t10, float& t11, float& t12,
    float& t20, float& t21, float& t22)
{
    const float n2 = x*x + y*y + z*z;
    const bool inside = (n2 < 1.0f);

    // Contracted branch (garbage if n2 ~ 0; discarded by select below).
    const float nrm = sqrtf(n2);
    const float inv = 1.0f / nrm;
    const float f   = (2.0f - inv) * inv;                // (2 - 1/n)/n
    const float s   = (2.0f * nrm - 1.0f) * inv * inv;   // (2n-1)/n^2
    const float c   = 2.0f * (1.0f - nrm) / (n2 * n2);   // 2(1-n)/n^4

    ox = inside ? x : f * x;
    oy = inside ? y : f * y;
    oz = inside ? z : f * z;

    // u = C x
    const float u0 = c00*x + c01*y + c02*z;
    const float u1 = c10*x + c11*y + c12*z;
    const float u2 = c20*x + c21*y + c22*z;
    const float q  = x*u0 + y*u1 + z*u2;     // x^T C x

    const float s2  = s * s;
    const float scc = s * c;
    const float c2q = c * c * q;

    t00 = inside ? c00 : s2*c00 + scc*(u0*x + x*u0) + c2q*x*x;
    t01 = inside ? c01 : s2*c01 + scc*(u0*y + x*u1) + c2q*x*y;
    t02 = inside ? c02 : s2*c02 + scc*(u0*z + x*u2) + c2q*x*z;
    t10 = inside ? c10 : s2*c10 + scc*(u1*x + y*u0) + c2q*y*x;
    t11 = inside ? c11 : s2*c11 + scc*(u1*y + y*u1) + c2q*y*y;
    t12 = inside ? c12 : s2*c12 + scc*(u1*z + y*u2) + c2q*y*z;
    t20 = inside ? c20 : s2*c20 + scc*(u2*x + z*u0) + c2q*z*x;
    t21 = inside ? c21 : s2*c21 + scc*(u2*y + z*u1) + c2q*z*y;
    t22 = inside ? c22 : s2*c22 + scc*(u2*z + z*u2) + c2q*z*z;
}

__global__ __launch_bounds__(BLOCK) void scene_contraction4_kernel(
    const float4* __restrict__ m4,
    const float4* __restrict__ c4,
    float4* __restrict__ om4,
    float4* __restrict__ oc4,
    const float* __restrict__ means,
    const float* __restrict__ cov,
    float* __restrict__ out_means,
    float* __restrict__ out_cov,
    int ngroups, int n)
{
    const int g = blockIdx.x * blockDim.x + threadIdx.x;

    if (g < ngroups) {
        const size_t mb = 3 * (size_t)g;   // float4 index into means
        const size_t cb = 9 * (size_t)g;   // float4 index into cov

        // 12 independent 16B loads
        const float4 Ma = m4[mb + 0];
        const float4 Mb = m4[mb + 1];
        const float4 Mc = m4[mb + 2];
        const float4 Ca = c4[cb + 0];
        const float4 Cb = c4[cb + 1];
        const float4 Cc = c4[cb + 2];
        const float4 Cd = c4[cb + 3];
        const float4 Ce = c4[cb + 4];
        const float4 Cf = c4[cb + 5];
        const float4 Cg = c4[cb + 6];
        const float4 Ch = c4[cb + 7];
        const float4 Ci = c4[cb + 8];

        const float mf[12] = {Ma.x,Ma.y,Ma.z,Ma.w, Mb.x,Mb.y,Mb.z,Mb.w, Mc.x,Mc.y,Mc.z,Mc.w};
        const float cf[36] = {Ca.x,Ca.y,Ca.z,Ca.w, Cb.x,Cb.y,Cb.z,Cb.w, Cc.x,Cc.y,Cc.z,Cc.w,
                              Cd.x,Cd.y,Cd.z,Cd.w, Ce.x,Ce.y,Ce.z,Ce.w, Cf.x,Cf.y,Cf.z,Cf.w,
                              Cg.x,Cg.y,Cg.z,Cg.w, Ch.x,Ch.y,Ch.z,Ch.w, Ci.x,Ci.y,Ci.z,Ci.w};
        float of[12], tf[36];

#pragma unroll
        for (int p = 0; p < 4; ++p) {
            contract_one(mf[3*p+0], mf[3*p+1], mf[3*p+2],
                         cf[9*p+0], cf[9*p+1], cf[9*p+2],
                         cf[9*p+3], cf[9*p+4], cf[9*p+5],
                         cf[9*p+6], cf[9*p+7], cf[9*p+8],
                         of[3*p+0], of[3*p+1], of[3*p+2],
                         tf[9*p+0], tf[9*p+1], tf[9*p+2],
                         tf[9*p+3], tf[9*p+4], tf[9*p+5],
                         tf[9*p+6], tf[9*p+7], tf[9*p+8]);
        }

        om4[mb + 0] = make_float4(of[0], of[1], of[2],  of[3]);
        om4[mb + 1] = make_float4(of[4], of[5], of[6],  of[7]);
        om4[mb + 2] = make_float4(of[8], of[9], of[10], of[11]);
#pragma unroll
        for (int k = 0; k < 9; ++k)
            oc4[cb + k] = make_float4(tf[4*k+0], tf[4*k+1], tf[4*k+2], tf[4*k+3]);
    } else if (g == ngroups) {
        // scalar tail: points [4*ngroups, n)
        for (int i = 4 * ngroups; i < n; ++i) {
            const size_t mbase = 3 * (size_t)i;
            const size_t cbase = 9 * (size_t)i;
            float ox, oy, oz, t00, t01, t02, t10, t11, t12, t20, t21, t22;
            contract_one(means[mbase+0], means[mbase+1], means[mbase+2],
                         cov[cbase+0], cov[cbase+1], cov[cbase+2],
                         cov[cbase+3], cov[cbase+4], cov[cbase+5],
                         cov[cbase+6], cov[cbase+7], cov[cbase+8],
                         ox, oy, oz,
                         t00, t01, t02, t10, t11, t12, t20, t21, t22);
            out_means[mbase+0] = ox; out_means[mbase+1] = oy; out_means[mbase+2] = oz;
            out_cov[cbase+0] = t00; out_cov[cbase+1] = t01; out_cov[cbase+2] = t02;
            out_cov[cbase+3] = t10; out_cov[cbase+4] = t11; out_cov[cbase+5] = t12;
            out_cov[cbase+6] = t20; out_cov[cbase+7] = t21; out_cov[cbase+8] = t22;
        }
    }
}

extern "C" void kernel_launch(void* const* d_in, const int* in_sizes, int n_in,
                              void* d_out, int out_size, void* d_ws, size_t ws_size,
                              hipStream_t stream) {
    const float* means = (const float*)d_in[0];   // [N,3]
    const float* cov   = (const float*)d_in[1];   // [N,3,3]
    const int n = in_sizes[0] / 3;

    float* out_means = (float*)d_out;                  // [N,3]
    float* out_cov   = (float*)d_out + (size_t)n * 3;  // [N,3,3]

    const int ngroups = n / 4;
    const int rem = n - 4 * ngroups;
    const int nthreads = ngroups + (rem ? 1 : 0);
    const int grid = (nthreads + BLOCK - 1) / BLOCK;

    hipLaunchKernelGGL(scene_contraction4_kernel, dim3(grid), dim3(BLOCK), 0, stream,
                       (const float4*)means, (const float4*)cov,
                       (float4*)out_means, (float4*)out_cov,
                       means, cov, out_means, out_cov,
                       ngroups, n);
}

// Round 4
// 34.520 us; speedup vs baseline: 1.8631x; 1.8631x over previous
//
#include <hip/hip_runtime.h>

// SceneContraction: f(x) = x if ||x||<1 else (2 - 1/||x||) x/||x||
// cov' = J cov J^T for ||x||>=1 (J = s I + c x x^T, s=(2n-1)/n^2, c=2(1-n)/n^4).
// R3: persistent blocks + double-buffered LDS staging via global_load_lds(16B)
//     + counted s_waitcnt vmcnt(3) + raw s_barrier (no full drain in loop),
//     so chunk k+1's HBM loads fly under chunk k's compute+store.
// Chunk = 256 points = 768 float4 (192 means-f4 ‖ 576 cov-f4), 12 KB/buffer.

#define BLOCK 256
#define CS    256      // points per chunk
#define GRID  2048

typedef const __attribute__((address_space(1))) void* glb_p;
typedef __attribute__((address_space(3))) void*       lds_p;

__device__ __forceinline__ void contract_one(
    float x, float y, float z,
    float c00, float c01, float c02,
    float c10, float c11, float c12,
    float c20, float c21, float c22,
    float& ox, float& oy, float& oz,
    float& t00, float& t01, float& t02,
    float& t10, float& t11, float& t12,
    float& t20, float& t21, float& t22)
{
    const float n2 = x*x + y*y + z*z;
    const bool inside = (n2 < 1.0f);

    const float nrm = sqrtf(n2);
    const float inv = 1.0f / nrm;
    const float f   = (2.0f - inv) * inv;                // (2 - 1/n)/n
    const float s   = (2.0f * nrm - 1.0f) * inv * inv;   // (2n-1)/n^2
    const float c   = 2.0f * (1.0f - nrm) / (n2 * n2);   // 2(1-n)/n^4

    ox = inside ? x : f * x;
    oy = inside ? y : f * y;
    oz = inside ? z : f * z;

    const float u0 = c00*x + c01*y + c02*z;
    const float u1 = c10*x + c11*y + c12*z;
    const float u2 = c20*x + c21*y + c22*z;
    const float q  = x*u0 + y*u1 + z*u2;

    const float s2  = s * s;
    const float scc = s * c;
    const float c2q = c * c * q;

    t00 = inside ? c00 : s2*c00 + scc*(u0*x + x*u0) + c2q*x*x;
    t01 = inside ? c01 : s2*c01 + scc*(u0*y + x*u1) + c2q*x*y;
    t02 = inside ? c02 : s2*c02 + scc*(u0*z + x*u2) + c2q*x*z;
    t10 = inside ? c10 : s2*c10 + scc*(u1*x + y*u0) + c2q*y*x;
    t11 = inside ? c11 : s2*c11 + scc*(u1*y + y*u1) + c2q*y*y;
    t12 = inside ? c12 : s2*c12 + scc*(u1*z + y*u2) + c2q*y*z;
    t20 = inside ? c20 : s2*c20 + scc*(u2*x + z*u0) + c2q*z*x;
    t21 = inside ? c21 : s2*c21 + scc*(u2*y + z*u1) + c2q*z*y;
    t22 = inside ? c22 : s2*c22 + scc*(u2*z + z*u2) + c2q*z*z;
}

__global__ __launch_bounds__(BLOCK) void scene_contraction_pipe_kernel(
    const float4* __restrict__ m4,
    const float4* __restrict__ c4,
    float4* __restrict__ om4,
    float4* __restrict__ oc4,
    const float* __restrict__ means,
    const float* __restrict__ cov,
    float* __restrict__ out_means,
    float* __restrict__ out_cov,
    int nchunks, int n)
{
    __shared__ __align__(16) float sbuf[2][3072];   // 2 x 12 KB

    const int tid  = threadIdx.x;
    const int wid  = tid >> 6;
    const int lane = tid & 63;

    // ---- tail points (beyond full chunks): scalar, last block ----
    if (blockIdx.x == gridDim.x - 1) {
        for (int i = nchunks * CS + tid; i < n; i += BLOCK) {
            const size_t mb = 3 * (size_t)i, cb = 9 * (size_t)i;
            float ox,oy,oz,t00,t01,t02,t10,t11,t12,t20,t21,t22;
            contract_one(means[mb+0], means[mb+1], means[mb+2],
                         cov[cb+0], cov[cb+1], cov[cb+2],
                         cov[cb+3], cov[cb+4], cov[cb+5],
                         cov[cb+6], cov[cb+7], cov[cb+8],
                         ox,oy,oz, t00,t01,t02,t10,t11,t12,t20,t21,t22);
            out_means[mb+0]=ox; out_means[mb+1]=oy; out_means[mb+2]=oz;
            out_cov[cb+0]=t00; out_cov[cb+1]=t01; out_cov[cb+2]=t02;
            out_cov[cb+3]=t10; out_cov[cb+4]=t11; out_cov[cb+5]=t12;
            out_cov[cb+6]=t20; out_cov[cb+7]=t21; out_cov[cb+8]=t22;
        }
    }

    // ---- contiguous chunk range for this block ----
    const int nb   = gridDim.x;
    const int per  = nchunks / nb;
    const int rem  = nchunks % nb;
    const int bid  = blockIdx.x;
    const int start = bid * per + (bid < rem ? bid : rem);
    const int cnt   = per + (bid < rem ? 1 : 0);
    if (cnt == 0) return;

    // stage chunk c into sbuf[buf]: 3 uniform gl_lds rounds/wave (12 wave-rounds)
    auto stage = [&](int buf, int c) {
        const float4* gm = m4 + (size_t)c * 192;
        const float4* gc = c4 + (size_t)c * 576;
#pragma unroll
        for (int r = 0; r < 3; ++r) {
            const int j = wid + 4 * r;                    // 0..11, wave-uniform
            const float4* src = (j < 3) ? (gm + 64 * j + lane)
                                        : (gc + 64 * (j - 3) + lane);
            __builtin_amdgcn_global_load_lds((glb_p)src,
                (lds_p)&sbuf[buf][256 * j + 4 * lane], 16, 0, 0);
        }
    };

    // prologue: stage first chunk, full drain once
    stage(0, start);
    asm volatile("s_waitcnt vmcnt(0)" ::: "memory");
    __builtin_amdgcn_s_barrier();

    int cur = 0;
    for (int k = 0; k < cnt; ++k) {
        const int c = start + k;
        const bool has_next = (k + 1 < cnt);
        if (has_next) stage(cur ^ 1, c + 1);   // async, stays in flight

        // ---- compute from sbuf[cur], write back in place (own slots only) ----
        {
            float* sf = sbuf[cur];
            const float x = sf[3*tid+0], y = sf[3*tid+1], z = sf[3*tid+2];
            const int cb = 768 + 9 * tid;
            const float c00 = sf[cb+0], c01 = sf[cb+1], c02 = sf[cb+2];
            const float c10 = sf[cb+3], c11 = sf[cb+4], c12 = sf[cb+5];
            const float c20 = sf[cb+6], c21 = sf[cb+7], c22 = sf[cb+8];
            float ox,oy,oz,t00,t01,t02,t10,t11,t12,t20,t21,t22;
            contract_one(x,y,z, c00,c01,c02,c10,c11,c12,c20,c21,c22,
                         ox,oy,oz, t00,t01,t02,t10,t11,t12,t20,t21,t22);
            sf[3*tid+0]=ox; sf[3*tid+1]=oy; sf[3*tid+2]=oz;
            sf[cb+0]=t00; sf[cb+1]=t01; sf[cb+2]=t02;
            sf[cb+3]=t10; sf[cb+4]=t11; sf[cb+5]=t12;
            sf[cb+6]=t20; sf[cb+7]=t21; sf[cb+8]=t22;
        }

        // writeback visible to all waves (do NOT drain vmcnt: stage-next in flight)
        asm volatile("s_waitcnt lgkmcnt(0)" ::: "memory");
        __builtin_amdgcn_s_barrier();

        // ---- coalesced store phase: LDS f4 -> global f4, same round mapping ----
#pragma unroll
        for (int r = 0; r < 3; ++r) {
            const int j = wid + 4 * r;
            const float4 v = *reinterpret_cast<const float4*>(&sbuf[cur][256 * j + 4 * lane]);
            if (j < 3) om4[(size_t)c * 192 + 64 * j + lane] = v;
            else       oc4[(size_t)c * 576 + 64 * (j - 3) + lane] = v;
        }

        // drain ONLY the next-chunk stage (oldest 3 vmem ops); stores stay in flight
        asm volatile("s_waitcnt vmcnt(3)" ::: "memory");
        __builtin_amdgcn_s_barrier();   // all waves: sbuf[cur^1] fully staged;
                                        // also fences store-phase reads before
                                        // next iter re-stages this buffer
        cur ^= 1;
    }
}

extern "C" void kernel_launch(void* const* d_in, const int* in_sizes, int n_in,
                              void* d_out, int out_size, void* d_ws, size_t ws_size,
                              hipStream_t stream) {
    const float* means = (const float*)d_in[0];   // [N,3]
    const float* cov   = (const float*)d_in[1];   // [N,3,3]
    const int n = in_sizes[0] / 3;

    float* out_means = (float*)d_out;                  // [N,3]
    float* out_cov   = (float*)d_out + (size_t)n * 3;  // [N,3,3]

    const int nchunks = n / CS;                        // full chunks
    const int grid = (nchunks < GRID) ? (nchunks > 0 ? nchunks : 1) : GRID;

    hipLaunchKernelGGL(scene_contraction_pipe_kernel, dim3(grid), dim3(BLOCK), 0, stream,
                       (const float4*)means, (const float4*)cov,
                       (float4*)out_means, (float4*)out_cov,
                       means, cov, out_means, out_cov,
                       nchunks, n);
}

// Round 9
// 34.493 us; speedup vs baseline: 1.8646x; 1.0008x over previous
//
#include <hip/hip_runtime.h>

// SceneContraction: f(x) = x if ||x||<1 else (2 - 1/||x||) x/||x||
// cov' = J cov J^T for ||x||>=1 (J = s I + c x x^T, s=(2n-1)/n^2, c=2(1-n)/n^4),
// cov otherwise.
// R8 = R6 resubmitted verbatim (containers died before benching R6/R7).
// R6 = R1 (LDS-staged float4 coalesced) + NON-TEMPORAL stores via native
//   clang ext_vector float4 (HIP's float4 class is rejected by the builtin).
//   Outputs are write-once: nt stores keep the 94 MB output stream from
//   evicting the (fully-L3-resident-capable) 96 MB input set across replays.

#define BLOCK 256

typedef float nfloat4 __attribute__((ext_vector_type(4)));

__global__ __launch_bounds__(BLOCK) void scene_contraction_kernel(
    const float* __restrict__ means,
    const float* __restrict__ cov,
    float* __restrict__ out_means,
    float* __restrict__ out_cov,
    int n)
{
    __shared__ float sm[BLOCK * 3];   // 3072 B
    __shared__ float sc[BLOCK * 9];   // 9216 B

    const int t  = threadIdx.x;
    const long p0 = (long)blockIdx.x * BLOCK;
    const int npts = (int)min((long)BLOCK, (long)n - p0);
    if (npts <= 0) return;

    // ---- coalesced load: means chunk ----
    {
        const int nf = 3 * npts;
        const int nq = nf >> 2;
        const nfloat4* g4 = (const nfloat4*)(means + 3L * p0);
        nfloat4* s4 = (nfloat4*)sm;
        for (int q = t; q < nq; q += BLOCK) s4[q] = g4[q];
        for (int r = (nq << 2) + t; r < nf; r += BLOCK) sm[r] = means[3L * p0 + r];
    }
    // ---- coalesced load: cov chunk ----
    {
        const int nf = 9 * npts;
        const int nq = nf >> 2;
        const nfloat4* g4 = (const nfloat4*)(cov + 9L * p0);
        nfloat4* s4 = (nfloat4*)sc;
        for (int q = t; q < nq; q += BLOCK) s4[q] = g4[q];
        for (int r = (nq << 2) + t; r < nf; r += BLOCK) sc[r] = cov[9L * p0 + r];
    }
    __syncthreads();

    const bool active = (t < npts);
    float ox=0, oy=0, oz=0;
    float t00=0,t01=0,t02=0,t10=0,t11=0,t12=0,t20=0,t21=0,t22=0;

    if (active) {
        const float x = sm[3*t + 0];
        const float y = sm[3*t + 1];
        const float z = sm[3*t + 2];

        const float c00 = sc[9*t + 0];
        const float c01 = sc[9*t + 1];
        const float c02 = sc[9*t + 2];
        const float c10 = sc[9*t + 3];
        const float c11 = sc[9*t + 4];
        const float c12 = sc[9*t + 5];
        const float c20 = sc[9*t + 6];
        const float c21 = sc[9*t + 7];
        const float c22 = sc[9*t + 8];

        const float n2 = x*x + y*y + z*z;
        const bool inside = (n2 < 1.0f);

        const float nrm = sqrtf(n2);
        const float inv = 1.0f / nrm;
        const float f   = (2.0f - inv) * inv;                 // (2 - 1/n)/n
        const float s   = (2.0f * nrm - 1.0f) * inv * inv;    // (2n-1)/n^2
        const float c   = 2.0f * (1.0f - nrm) / (n2 * n2);    // 2(1-n)/n^4

        ox = inside ? x : f * x;
        oy = inside ? y : f * y;
        oz = inside ? z : f * z;

        const float u0 = c00*x + c01*y + c02*z;
        const float u1 = c10*x + c11*y + c12*z;
        const float u2 = c20*x + c21*y + c22*z;
        const float q  = x*u0 + y*u1 + z*u2;

        const float s2  = s * s;
        const float scc = s * c;
        const float c2q = c * c * q;

        t00 = inside ? c00 : s2*c00 + scc*(u0*x + x*u0) + c2q*x*x;
        t01 = inside ? c01 : s2*c01 + scc*(u0*y + x*u1) + c2q*x*y;
        t02 = inside ? c02 : s2*c02 + scc*(u0*z + x*u2) + c2q*x*z;
        t10 = inside ? c10 : s2*c10 + scc*(u1*x + y*u0) + c2q*y*x;
        t11 = inside ? c11 : s2*c11 + scc*(u1*y + y*u1) + c2q*y*y;
        t12 = inside ? c12 : s2*c12 + scc*(u1*z + y*u2) + c2q*y*z;
        t20 = inside ? c20 : s2*c20 + scc*(u2*x + z*u0) + c2q*z*x;
        t21 = inside ? c21 : s2*c21 + scc*(u2*y + z*u1) + c2q*z*y;
        t22 = inside ? c22 : s2*c22 + scc*(u2*z + z*u2) + c2q*z*z;
    }
    __syncthreads();

    if (active) {
        sm[3*t + 0] = ox;  sm[3*t + 1] = oy;  sm[3*t + 2] = oz;
        sc[9*t + 0] = t00; sc[9*t + 1] = t01; sc[9*t + 2] = t02;
        sc[9*t + 3] = t10; sc[9*t + 4] = t11; sc[9*t + 5] = t12;
        sc[9*t + 6] = t20; sc[9*t + 7] = t21; sc[9*t + 8] = t22;
    }
    __syncthreads();

    // ---- coalesced NON-TEMPORAL store ----
    {
        const int nf = 3 * npts;
        const int nq = nf >> 2;
        nfloat4* g4 = (nfloat4*)(out_means + 3L * p0);
        const nfloat4* s4 = (const nfloat4*)sm;
        for (int q = t; q < nq; q += BLOCK) __builtin_nontemporal_store(s4[q], &g4[q]);
        for (int r = (nq << 2) + t; r < nf; r += BLOCK)
            __builtin_nontemporal_store(sm[r], &out_means[3L * p0 + r]);
    }
    {
        const int nf = 9 * npts;
        const int nq = nf >> 2;
        nfloat4* g4 = (nfloat4*)(out_cov + 9L * p0);
        const nfloat4* s4 = (const nfloat4*)sc;
        for (int q = t; q < nq; q += BLOCK) __builtin_nontemporal_store(s4[q], &g4[q]);
        for (int r = (nq << 2) + t; r < nf; r += BLOCK)
            __builtin_nontemporal_store(sc[r], &out_cov[9L * p0 + r]);
    }
}

extern "C" void kernel_launch(void* const* d_in, const int* in_sizes, int n_in,
                              void* d_out, int out_size, void* d_ws, size_t ws_size,
                              hipStream_t stream) {
    const float* means = (const float*)d_in[0];   // [N,3]
    const float* cov   = (const float*)d_in[1];   // [N,3,3]
    const int n = in_sizes[0] / 3;

    float* out_means = (float*)d_out;                  // [N,3]
    float* out_cov   = (float*)d_out + (size_t)n * 3;  // [N,3,3]

    const int grid = (n + BLOCK - 1) / BLOCK;
    hipLaunchKernelGGL(scene_contraction_kernel, dim3(grid), dim3(BLOCK), 0, stream,
                       means, cov, out_means, out_cov, n);
}